// Round 1
// 334.890 us; speedup vs baseline: 1.1233x; 1.1233x over previous
//
#include <hip/hip_runtime.h>
#include <hip/hip_fp16.h>
#include <math.h>

#define F_IN 128
#define H 16
#define C 40
#define K_HOPS 10
#define ALPHA 0.1f
#define BN_EPS 1e-5f

#define RB 512          // nodes per bucket
#define RB_BITS 9
#define NBKT_MAX 256    // ceil(100000/512)=196
#define SRC_MASK 0x1FFFF
#define PADQ 16         // node segment padded to multiple of 16 entries (even pair split)
#define NDUMMY 2048     // dummy zero rows spread over L2

typedef int v4i __attribute__((ext_vector_type(4)));

// ---------------- zero: gbcnt=0, stats=0, dummy rows of both tables = 0 ----------------
__global__ void k_zero(int* __restrict__ gbcnt, float* __restrict__ stats,
                       __half* __restrict__ h1h, __half* __restrict__ hh, int n) {
    int id = blockIdx.x * blockDim.x + threadIdx.x;
    if (id < NBKT_MAX) gbcnt[id] = 0;
    if (id < 32) stats[id] = 0.0f;
    // NDUMMY rows x 16 halves = 64KB per table = 16384 ints
    int* z1 = (int*)(h1h + (size_t)n * H);
    int* z2 = (int*)(hh + (size_t)n * H);
    if (id < NDUMMY * H / 2) { z1[id] = 0; z2[id] = 0; }
}

// ---------------- bucket counts ----------------
__global__ __launch_bounds__(256) void k_bcnt(const int* __restrict__ dst,
                                              int* __restrict__ gbcnt, int e) {
    __shared__ int hist[NBKT_MAX];
    int t = threadIdx.x;
    if (t < NBKT_MAX) hist[t] = 0;
    __syncthreads();
    int base = blockIdx.x * 4096;
    int endi = base + 4096; if (endi > e) endi = e;
    for (int i = base + t; i < endi; i += 256)
        atomicAdd(&hist[dst[i] >> RB_BITS], 1);
    __syncthreads();
    if (t < NBKT_MAX && hist[t]) atomicAdd(&gbcnt[t], hist[t]);
}

// ---------------- scans: raw bucket offsets (temp) + padded csr bases ----------------
__global__ __launch_bounds__(256) void k_bscan(const int* __restrict__ gbcnt,
                                               int* __restrict__ gboff,
                                               int* __restrict__ gcur,
                                               int* __restrict__ gcsr, int nbkt) {
    __shared__ int sd[256];
    int t = threadIdx.x;
    int v = (t < nbkt) ? gbcnt[t] : 0;
    sd[t] = v;
    __syncthreads();
    for (int off = 1; off < 256; off <<= 1) {
        int tmp = (t >= off) ? sd[t - off] : 0;
        __syncthreads();
        sd[t] += tmp;
        __syncthreads();
    }
    if (t < nbkt) { int o = sd[t] - v; gboff[t] = o; gcur[t] = o; }
    if (t == nbkt - 1) gboff[nbkt] = sd[t];
    __syncthreads();
    // padded csr capacity: worst-case per-node padding (PADQ-1 each)
    int cap = (t < nbkt) ? ((v + RB * (PADQ - 1) + PADQ - 1) & ~(PADQ - 1)) : 0;
    sd[t] = cap;
    __syncthreads();
    for (int off = 1; off < 256; off <<= 1) {
        int tmp = (t >= off) ? sd[t - off] : 0;
        __syncthreads();
        sd[t] += tmp;
        __syncthreads();
    }
    if (t < nbkt) gcsr[t] = sd[t] - cap;
}

// ---------------- bin edges into bucket runs (dense 4B writes) ----------------
#define BIN_CHUNK 4096
__global__ __launch_bounds__(256) void k_bin(const int* __restrict__ src,
                                             const int* __restrict__ dst,
                                             int* __restrict__ gcur,
                                             int* __restrict__ temp, int e) {
    __shared__ int hist[NBKT_MAX];
    __shared__ int lcur[NBKT_MAX];
    int t = threadIdx.x;
    if (t < NBKT_MAX) hist[t] = 0;
    __syncthreads();
    int base = blockIdx.x * BIN_CHUNK;
    int ss[16], dd[16];
#pragma unroll
    for (int i = 0; i < 16; ++i) {
        int idx = base + i * 256 + t;
        if (idx < e) {
            ss[i] = src[idx]; dd[i] = dst[idx];
            atomicAdd(&hist[dd[i] >> RB_BITS], 1);
        } else ss[i] = -1;
    }
    __syncthreads();
    if (t < NBKT_MAX) {
        int h = hist[t];
        lcur[t] = h ? atomicAdd(&gcur[t], h) : 0;
    }
    __syncthreads();
#pragma unroll
    for (int i = 0; i < 16; ++i) {
        if (ss[i] >= 0) {
            int d = dd[i];
            int b = d >> RB_BITS;
            int pos = atomicAdd(&lcur[b], 1);
            temp[pos] = ss[i] | ((d & (RB - 1)) << 17);
        }
    }
}

// ---------------- per-bucket counting sort -> padded CSR; deg->dinv;
//                  degree-sorted node order (ostart/oend/onode) ----------------
__global__ __launch_bounds__(256) void k_sort(const int* __restrict__ gboff,
                                              const int* __restrict__ gcsr,
                                              const int* __restrict__ temp,
                                              int* __restrict__ csr,
                                              int* __restrict__ ostart,
                                              int* __restrict__ oend,
                                              int* __restrict__ onode,
                                              float* __restrict__ dinv, int n) {
    __shared__ int hist[RB];
    __shared__ int psum[256];
    __shared__ int qh[64];
    __shared__ int qb[64];
    int t = threadIdx.x;
    int bkt = blockIdx.x;
    int start = gboff[bkt], endi = gboff[bkt + 1];
    hist[t] = 0; hist[t + 256] = 0;
    if (t < 64) qh[t] = 0;
    __syncthreads();
    for (int k = start + t; k < endi; k += 256)
        atomicAdd(&hist[temp[k] >> 17], 1);
    __syncthreads();
    int node0 = bkt * RB;
    int h0 = hist[2 * t], h1v = hist[2 * t + 1];
    int p0 = (h0 + PADQ - 1) & ~(PADQ - 1);
    int p1 = (h1v + PADQ - 1) & ~(PADQ - 1);
    int na = node0 + 2 * t, nb = na + 1;
    bool va = (na < n), vb = (nb < n);
    if (va) dinv[na] = rsqrtf((float)(h0 + 1));
    if (vb) dinv[nb] = rsqrtf((float)(h1v + 1));
    psum[t] = p0 + p1;
    __syncthreads();
    for (int off = 1; off < 256; off <<= 1) {
        int tmp = (t >= off) ? psum[t - off] : 0;
        __syncthreads();
        psum[t] += tmp;
        __syncthreads();
    }
    int pexcl = psum[t] - (p0 + p1);
    int cbase = gcsr[bkt];
    int s0 = cbase + pexcl, s1 = s0 + p0;
    // degree bins (iterations = padded/16); invalid nodes go to bin 0 with onode=-1
    int q0 = va ? min(p0 >> 4, 63) : 0;
    int q1 = vb ? min(p1 >> 4, 63) : 0;
    int r0 = atomicAdd(&qh[q0], 1);
    int r1 = atomicAdd(&qh[q1], 1);
    // write per-node scatter cursors (own slots only, safe)
    hist[2 * t] = s0; hist[2 * t + 1] = s1;
    __syncthreads();
    if (t == 0) {
        int run = 0;
        for (int i = 0; i < 64; ++i) { qb[i] = run; run += qh[i]; }
    }
    __syncthreads();
    int ga = node0 + qb[q0] + r0;
    int gb = node0 + qb[q1] + r1;
    ostart[ga] = s0; oend[ga] = s0 + p0; onode[ga] = va ? na : -1;
    ostart[gb] = s1; oend[gb] = s1 + p1; onode[gb] = vb ? nb : -1;
    // scatter edges
    for (int k = start + t; k < endi; k += 256) {
        int v = temp[k];
        int dl = v >> 17;
        int pos = atomicAdd(&hist[dl], 1);
        csr[pos] = v & SRC_MASK;
    }
    __syncthreads();
    // pad with distinct dummy zero rows
    for (int i = s0 + h0;  i < s0 + p0; ++i) csr[i] = n + (i & (NDUMMY - 1));
    for (int i = s1 + h1v; i < s1 + p1; ++i) csr[i] = n + (i & (NDUMMY - 1));
}

// ---------------- h1' = dinv .* (x @ W1) -> fp16 table ----------------
__global__ __launch_bounds__(256) void k_mm1(const float* __restrict__ x,
                                             const float* __restrict__ W1,
                                             const float* __restrict__ dinv,
                                             __half* __restrict__ h1h, int n) {
    __shared__ float xs[16 * 132];
    __shared__ float ws[128 * 16];
    int t = threadIdx.x;
    int node0 = blockIdx.x * 16;
#pragma unroll
    for (int r = 0; r < 8; ++r) {
        int idx = t + r * 256;
        int nl = idx >> 7, k = idx & 127;
        int nn = node0 + nl; if (nn >= n) nn = n - 1;
        xs[nl * 132 + k] = x[(size_t)nn * F_IN + k];
        ws[idx] = W1[idx];
    }
    __syncthreads();
    int nl = t >> 4, j = t & 15;
    float acc = 0.0f;
#pragma unroll 8
    for (int k = 0; k < 128; ++k)
        acc = fmaf(xs[nl * 132 + k], ws[k * 16 + j], acc);
    int node = node0 + nl;
    if (node < n) h1h[(size_t)node * H + j] = __float2half(acc * dinv[node]);
}

__device__ __forceinline__ void acc8(float* a, int4 gv) {
    const __half2* h = reinterpret_cast<const __half2*>(&gv);
    float2 f0 = __half22float2(h[0]);
    float2 f1 = __half22float2(h[1]);
    float2 f2 = __half22float2(h[2]);
    float2 f3 = __half22float2(h[3]);
    a[0] += f0.x; a[1] += f0.y; a[2] += f1.x; a[3] += f1.y;
    a[4] += f2.x; a[5] += f2.y; a[6] += f3.x; a[7] += f3.y;
}

// ---------------- gather conv1: 4 lanes/node (2 pairs x 16B), degree-sorted order;
//                  + bias + ReLU + BN stats ----------------
__global__ __launch_bounds__(256) void k_gather1(const int* __restrict__ ostart,
                                                 const int* __restrict__ oend,
                                                 const int* __restrict__ onode,
                                                 const int* __restrict__ csr,
                                                 const __half* __restrict__ h1h,
                                                 const float* __restrict__ dinv,
                                                 const float* __restrict__ b1,
                                                 float* __restrict__ hout,
                                                 float* __restrict__ stats, int n) {
    __shared__ float sm[32];
    __shared__ float b1s[16];
    int t = threadIdx.x;
    if (t < 32) sm[t] = 0.0f;
    if (t < 16) b1s[t] = b1[t];
    __syncthreads();
    int idx = blockIdx.x * 256 + t;
    int g = idx >> 2;
    int L = idx & 3, p = L >> 1, jj = L & 1;
    int node = __builtin_nontemporal_load(onode + g);
    float a[8];
#pragma unroll
    for (int k = 0; k < 8; ++k) a[k] = 0.0f;
    const int4* tab = reinterpret_cast<const int4*>(h1h);
    if (node >= 0) {
        int c  = (__builtin_nontemporal_load(ostart + g) >> 2) + (p << 1);
        int ce = __builtin_nontemporal_load(oend + g) >> 2;
        const v4i* csr4 = reinterpret_cast<const v4i*>(csr);
        for (; c < ce; c += 4) {
            v4i e0 = __builtin_nontemporal_load(csr4 + c);
            v4i e1 = __builtin_nontemporal_load(csr4 + c + 1);
            int4 g0 = tab[(size_t)e0.x * 2 + jj];
            int4 g1 = tab[(size_t)e0.y * 2 + jj];
            int4 g2 = tab[(size_t)e0.z * 2 + jj];
            int4 g3 = tab[(size_t)e0.w * 2 + jj];
            int4 g4 = tab[(size_t)e1.x * 2 + jj];
            int4 g5 = tab[(size_t)e1.y * 2 + jj];
            int4 g6 = tab[(size_t)e1.z * 2 + jj];
            int4 g7 = tab[(size_t)e1.w * 2 + jj];
            acc8(a, g0); acc8(a, g1); acc8(a, g2); acc8(a, g3);
            acc8(a, g4); acc8(a, g5); acc8(a, g6); acc8(a, g7);
        }
    }
    // combine the two pairs (lane ^ 2)
#pragma unroll
    for (int k = 0; k < 8; ++k) a[k] += __shfl_xor(a[k], 2);
    float din = 0.0f;
    int4 sv = make_int4(0, 0, 0, 0);
    if (node >= 0) {
        din = dinv[node];
        sv = tab[(size_t)node * 2 + jj];
    }
    float v[8];
    {
        const __half2* h = reinterpret_cast<const __half2*>(&sv);
        float2 f0 = __half22float2(h[0]), f1 = __half22float2(h[1]);
        float2 f2 = __half22float2(h[2]), f3 = __half22float2(h[3]);
        float s8[8] = { f0.x, f0.y, f1.x, f1.y, f2.x, f2.y, f3.x, f3.y };
        bool writer = (node >= 0) && (p == 0);
#pragma unroll
        for (int k = 0; k < 8; ++k) {
            float val = fmaxf(din * (a[k] + s8[k]) + b1s[jj * 8 + k], 0.0f);
            v[k] = writer ? val : 0.0f;
        }
        if (writer) {
            float4* o = reinterpret_cast<float4*>(hout + (size_t)node * H + jj * 8);
            o[0] = make_float4(v[0], v[1], v[2], v[3]);
            o[1] = make_float4(v[4], v[5], v[6], v[7]);
        }
    }
    // BN stats: reduce over wave (p1 lanes are zero, so each node counted once)
#pragma unroll
    for (int k = 0; k < 8; ++k) {
        float s1 = v[k], s2 = v[k] * v[k];
        s1 += __shfl_xor(s1, 2);  s2 += __shfl_xor(s2, 2);
        s1 += __shfl_xor(s1, 4);  s2 += __shfl_xor(s2, 4);
        s1 += __shfl_xor(s1, 8);  s2 += __shfl_xor(s2, 8);
        s1 += __shfl_xor(s1, 16); s2 += __shfl_xor(s2, 16);
        s1 += __shfl_xor(s1, 32); s2 += __shfl_xor(s2, 32);
        if ((t & 63) < 2) {
            atomicAdd(&sm[jj * 8 + k], s1);
            atomicAdd(&sm[16 + jj * 8 + k], s2);
        }
    }
    __syncthreads();
    if (t < 32) atomicAdd(&stats[t], sm[t]);
}

// ---------------- BN coefficients ----------------
__global__ void k_bncoef(float* __restrict__ stats, const float* __restrict__ gamma,
                         const float* __restrict__ beta, float nf) {
    int j = threadIdx.x;
    if (j < 16) {
        float mean = stats[j] / nf;
        float var = stats[16 + j] / nf - mean * mean;
        float a = gamma[j] * rsqrtf(var + BN_EPS);
        float c = beta[j] - mean * a;
        stats[j] = a;
        stats[16 + j] = c;
    }
}

// ---------------- BN apply + K_HOPS residual blocks -> scaled fp16 table ----------------
__global__ __launch_bounds__(256) void k_hops(const float* __restrict__ h,
                                              __half* __restrict__ hh,
                                              const float* __restrict__ stats,
                                              const float* __restrict__ Wl,
                                              const float* __restrict__ bl,
                                              const float* __restrict__ dinv, int n) {
    __shared__ float wl[256], bls[16], av[16], cv[16];
    int t = threadIdx.x;
    // transposed layout: wl[j*16+k] = Wl[k*16+j] -> contiguous k (ds_read_b128)
    wl[t] = Wl[(t & 15) * 16 + (t >> 4)];
    if (t < 16) { bls[t] = bl[t]; av[t] = stats[t]; cv[t] = stats[16 + t]; }
    __syncthreads();
    int node = blockIdx.x * 256 + t;
    if (node >= n) return;
    float hr[16];
    {
        const float4* hp = reinterpret_cast<const float4*>(h + (size_t)node * H);
        float4 v0 = hp[0], v1 = hp[1], v2 = hp[2], v3 = hp[3];
        hr[0] = v0.x; hr[1] = v0.y; hr[2] = v0.z; hr[3] = v0.w;
        hr[4] = v1.x; hr[5] = v1.y; hr[6] = v1.z; hr[7] = v1.w;
        hr[8] = v2.x; hr[9] = v2.y; hr[10] = v2.z; hr[11] = v2.w;
        hr[12] = v3.x; hr[13] = v3.y; hr[14] = v3.z; hr[15] = v3.w;
    }
#pragma unroll
    for (int j = 0; j < 16; ++j) hr[j] = hr[j] * av[j] + cv[j];
    for (int it = 0; it < K_HOPS; ++it) {
        float tmp[16];
#pragma unroll
        for (int j = 0; j < 16; ++j) {
            float a = bls[j];
#pragma unroll
            for (int k = 0; k < 16; ++k) a = fmaf(hr[k], wl[j * 16 + k], a);
            tmp[j] = fmaxf(a, 0.0f);
        }
#pragma unroll
        for (int j = 0; j < 16; ++j) hr[j] = ALPHA * tmp[j] + (1.0f - ALPHA) * hr[j];
    }
    {
        float din = dinv[node];
        __half2 ph[8];
#pragma unroll
        for (int i = 0; i < 8; ++i)
            ph[i] = __floats2half2_rn(hr[2 * i] * din, hr[2 * i + 1] * din);
        int4* hp = reinterpret_cast<int4*>(hh + (size_t)node * H);
        hp[0] = *reinterpret_cast<int4*>(&ph[0]);
        hp[1] = *reinterpret_cast<int4*>(&ph[4]);
    }
}

// ---------------- gather conv2: 4 lanes/node (2 pairs x 16B); + self-loop ----------------
__global__ __launch_bounds__(256) void k_gather2(const int* __restrict__ ostart,
                                                 const int* __restrict__ oend,
                                                 const int* __restrict__ onode,
                                                 const int* __restrict__ csr,
                                                 const __half* __restrict__ hh,
                                                 const float* __restrict__ dinv,
                                                 float* __restrict__ agg, int n) {
    int t = threadIdx.x;
    int idx = blockIdx.x * 256 + t;
    int g = idx >> 2;
    int L = idx & 3, p = L >> 1, jj = L & 1;
    int node = __builtin_nontemporal_load(onode + g);
    float a[8];
#pragma unroll
    for (int k = 0; k < 8; ++k) a[k] = 0.0f;
    const int4* tab = reinterpret_cast<const int4*>(hh);
    if (node >= 0) {
        int c  = (__builtin_nontemporal_load(ostart + g) >> 2) + (p << 1);
        int ce = __builtin_nontemporal_load(oend + g) >> 2;
        const v4i* csr4 = reinterpret_cast<const v4i*>(csr);
        for (; c < ce; c += 4) {
            v4i e0 = __builtin_nontemporal_load(csr4 + c);
            v4i e1 = __builtin_nontemporal_load(csr4 + c + 1);
            int4 g0 = tab[(size_t)e0.x * 2 + jj];
            int4 g1 = tab[(size_t)e0.y * 2 + jj];
            int4 g2 = tab[(size_t)e0.z * 2 + jj];
            int4 g3 = tab[(size_t)e0.w * 2 + jj];
            int4 g4 = tab[(size_t)e1.x * 2 + jj];
            int4 g5 = tab[(size_t)e1.y * 2 + jj];
            int4 g6 = tab[(size_t)e1.z * 2 + jj];
            int4 g7 = tab[(size_t)e1.w * 2 + jj];
            acc8(a, g0); acc8(a, g1); acc8(a, g2); acc8(a, g3);
            acc8(a, g4); acc8(a, g5); acc8(a, g6); acc8(a, g7);
        }
    }
#pragma unroll
    for (int k = 0; k < 8; ++k) a[k] += __shfl_xor(a[k], 2);
    if (node >= 0 && p == 0) {
        float din = dinv[node];
        int4 sv = tab[(size_t)node * 2 + jj];
        const __half2* h = reinterpret_cast<const __half2*>(&sv);
        float2 f0 = __half22float2(h[0]), f1 = __half22float2(h[1]);
        float2 f2 = __half22float2(h[2]), f3 = __half22float2(h[3]);
        float s8[8] = { f0.x, f0.y, f1.x, f1.y, f2.x, f2.y, f3.x, f3.y };
        float v[8];
#pragma unroll
        for (int k = 0; k < 8; ++k) v[k] = din * (a[k] + s8[k]);
        float4* o = reinterpret_cast<float4*>(agg + (size_t)node * H + jj * 8);
        o[0] = make_float4(v[0], v[1], v[2], v[3]);
        o[1] = make_float4(v[4], v[5], v[6], v[7]);
    }
}

// ---------------- final: agg2 @ W2 + b2 -> log_softmax ----------------
__global__ __launch_bounds__(256) void k_final(const float* __restrict__ agg2,
                                               const float* __restrict__ W2,
                                               const float* __restrict__ b2,
                                               float* __restrict__ out, int n) {
    __shared__ float w2s[16 * 40];
    __shared__ float b2s[40];
    __shared__ float ostage[40 * 257];
    int t = threadIdx.x;
    for (int i = t; i < 640; i += 256) w2s[i] = W2[i];
    if (t < 40) b2s[t] = b2[t];
    __syncthreads();
    int node = blockIdx.x * 256 + t;
    if (node < n) {
        float g[16];
        const float4* ap = reinterpret_cast<const float4*>(agg2 + (size_t)node * H);
#pragma unroll
        for (int r = 0; r < 4; ++r) {
            float4 a = ap[r];
            g[r * 4 + 0] = a.x; g[r * 4 + 1] = a.y; g[r * 4 + 2] = a.z; g[r * 4 + 3] = a.w;
        }
        float z[40];
#pragma unroll
        for (int j = 0; j < 40; ++j) {
            float a = b2s[j];
#pragma unroll
            for (int k = 0; k < 16; ++k) a = fmaf(g[k], w2s[k * 40 + j], a);
            z[j] = a;
        }
        float m = z[0];
#pragma unroll
        for (int j = 1; j < 40; ++j) m = fmaxf(m, z[j]);
        float s = 0.0f;
#pragma unroll
        for (int j = 0; j < 40; ++j) s += expf(z[j] - m);
        float lse = m + logf(s);
#pragma unroll
        for (int j = 0; j < 40; ++j) ostage[j * 257 + t] = z[j] - lse;
    }
    __syncthreads();
    int nodes = n - blockIdx.x * 256;
    if (nodes > 256) nodes = 256;
    int total = nodes * 40;
    size_t base = (size_t)blockIdx.x * 256 * 40;
    for (int i = t; i < total; i += 256) {
        int nl = i / 40;
        int j = i - nl * 40;
        out[base + i] = ostage[j * 257 + nl];
    }
}

extern "C" void kernel_launch(void* const* d_in, const int* in_sizes, int n_in,
                              void* d_out, int out_size, void* d_ws, size_t ws_size,
                              hipStream_t stream) {
    const float* x     = (const float*)d_in[0];
    const int*   src   = (const int*)d_in[1];
    const int*   dst   = (const int*)d_in[2];
    const float* W1    = (const float*)d_in[3];
    const float* b1    = (const float*)d_in[4];
    const float* gamma = (const float*)d_in[5];
    const float* beta  = (const float*)d_in[6];
    const float* Wl    = (const float*)d_in[7];
    const float* bl    = (const float*)d_in[8];
    const float* W2    = (const float*)d_in[9];
    const float* b2    = (const float*)d_in[10];
    float* out = (float*)d_out;

    int n = in_sizes[0] / F_IN;   // 100000
    int e = in_sizes[1];          // 3200000
    int nbkt = (n + RB - 1) >> RB_BITS;   // 196
    int nAlign = (n + 15) & ~15;
    int nG = nbkt * RB;                                      // ordered-node slots
    size_t csrCap = (size_t)e + (size_t)nG * (PADQ - 1) + (size_t)nbkt * PADQ + 64;
    size_t hTileB = (size_t)nAlign * H * 4;                  // 6.4 MB
    size_t unionB = (size_t)e * 4;                           // temp (12.8 MB)
    if (unionB < 2 * hTileB) unionB = 2 * hTileB;            // also holds hbuf+agg2 later

    char* wsb = (char*)d_ws;
    int*    csr      = (int*)wsb;      wsb += csrCap * 4;
    char*   uni      = wsb;            wsb += unionB;
    int*    temp     = (int*)uni;                  // alive: k_bin .. k_sort
    float*  hbuf     = (float*)uni;                // alive: k_gather1 .. k_hops
    float*  agg2     = (float*)(uni + hTileB);     // alive: k_gather2 .. k_final
    int*    ostart   = (int*)wsb;      wsb += (size_t)(nG + 16) * 4;
    int*    oend     = (int*)wsb;      wsb += (size_t)(nG + 16) * 4;
    int*    onode    = (int*)wsb;      wsb += (size_t)(nG + 16) * 4;
    float*  dinv     = (float*)wsb;    wsb += (size_t)nAlign * 4;
    int*    gbcnt    = (int*)wsb;      wsb += NBKT_MAX * 4;
    int*    gboff    = (int*)wsb;      wsb += (NBKT_MAX + 16) * 4;
    int*    gcur     = (int*)wsb;      wsb += NBKT_MAX * 4;
    int*    gcsr     = (int*)wsb;      wsb += (NBKT_MAX + 16) * 4;
    float*  stats    = (float*)wsb;    wsb += 64 * 4;
    __half* h1h      = (__half*)wsb;   wsb += (size_t)(nAlign + NDUMMY + 16) * H * 2;
    __half* hh       = (__half*)wsb;   wsb += (size_t)(nAlign + NDUMMY + 16) * H * 2;

    int nbE = (e + 4095) / 4096;   // 782

    k_zero<<<64, 256, 0, stream>>>(gbcnt, stats, h1h, hh, n);
    k_bcnt<<<nbE, 256, 0, stream>>>(dst, gbcnt, e);
    k_bscan<<<1, 256, 0, stream>>>(gbcnt, gboff, gcur, gcsr, nbkt);
    k_bin<<<(e + BIN_CHUNK - 1) / BIN_CHUNK, 256, 0, stream>>>(src, dst, gcur, temp, e);
    k_sort<<<nbkt, 256, 0, stream>>>(gboff, gcsr, temp, csr, ostart, oend, onode, dinv, n);
    k_mm1<<<(n + 15) / 16, 256, 0, stream>>>(x, W1, dinv, h1h, n);
    k_gather1<<<nbkt * 8, 256, 0, stream>>>(ostart, oend, onode, csr, h1h, dinv, b1, hbuf, stats, n);
    k_bncoef<<<1, 16, 0, stream>>>(stats, gamma, beta, (float)n);
    k_hops<<<(n + 255) / 256, 256, 0, stream>>>(hbuf, hh, stats, Wl, bl, dinv, n);
    k_gather2<<<nbkt * 8, 256, 0, stream>>>(ostart, oend, onode, csr, hh, dinv, agg2, n);
    k_final<<<(n + 255) / 256, 256, 0, stream>>>(agg2, W2, b2, out, n);
}